// Round 11
// baseline (272.007 us; speedup 1.0000x reference)
//
#include <hip/hip_runtime.h>
#include <hip/hip_bf16.h>

typedef __attribute__((ext_vector_type(8))) _Float16 half8;
typedef __attribute__((ext_vector_type(2))) _Float16 hf2;
typedef __attribute__((ext_vector_type(2))) __fp16 fp16x2;
typedef __attribute__((ext_vector_type(4))) float f32x4;
typedef __attribute__((ext_vector_type(16))) float f32x16;

union UH8 {
  half8 v;
  unsigned long long q[2];
  unsigned int w[4];
};
union U32H {
  unsigned int u;
  hf2 h;
};

__device__ __forceinline__ unsigned int pkh(float lo, float hi) {
  union { fp16x2 h; unsigned int u; } c;
  c.h = __builtin_amdgcn_cvt_pkrtz(lo, hi);
  return c.u;
}

constexpr int S_LEN = 2048;
constexpr int D_DIM = 64;
constexpr int KVB   = 64;     // kv tile rows
constexpr int QB    = 128;    // q rows per block (4 waves x 32)
constexpr int NCHK  = 512;    // 16B chunks per 64x64 fp16 tile (8 KB)
constexpr int NT    = S_LEN / KVB;
constexpr float LOG2E = 1.4426950408889634f;
constexpr float INV_D_QTR = 0.35355339059327373f;  // 1 / 64^0.25
constexpr float THR_L2 = 13.0f;  // defer-max: P <= 2^13, fp16-safe (max 65504)

// Paired-row swizzled tile layout (K and V^T), all accesses ds_*_b128:
//   physical chunk = (row>>1)*16 + ((row&1)<<3) + (cc ^ ((row>>1)&7))

__global__ __launch_bounds__(256, 4) void attn_fwd(
    const float* __restrict__ Q, const float* __restrict__ K,
    const float* __restrict__ V, float* __restrict__ O)
{
  const int tid  = threadIdx.x;
  const int w    = tid >> 6;      // wave 0..3
  const int lane = tid & 63;
  const int q32  = lane & 31;     // q-row within wave tile / MFMA m,n index
  const int h    = lane >> 5;     // half-wave index

  // XCD-aware bijective swizzle (1024 = 8 x 128)
  const int bid = blockIdx.x;
  const int wg  = (bid & 7) * 128 + (bid >> 3);
  const int qb  = wg & 15;        // q-block within head
  const int bh  = wg >> 4;        // batch*head

  const int q0 = qb * QB;

  __shared__ UH8 KsB[2][NCHK];  // K tile [kv][d] fp16, dbuf (read early in segment)
  __shared__ UH8 VtB[3][NCHK];  // V^T tile [d][kv] fp16, TRIPLE buf (read 1 tile late)

  const size_t base = (size_t)bh * S_LEN * D_DIM;

  // ---- staging ownership ----
  const int kr  = tid >> 3;            // K row 0..31 (and +32)
  const int kcc = tid & 7;             // K chunk within row

  float4 ka0, kb0, ka1, kb1;
  float va[8], vb[8];

  auto PREF = [&](int tt) {
    const int kv0 = tt * KVB;
    const float* kp = K + base + (size_t)(kv0 + kr) * D_DIM + kcc * 8;
    ka0 = *(const float4*)kp;
    kb0 = *(const float4*)(kp + 4);
    const float* kp1 = kp + 32 * D_DIM;
    ka1 = *(const float4*)kp1;
    kb1 = *(const float4*)(kp1 + 4);
    const float* vp = V + base + (size_t)(kv0 + w * 16) * D_DIM + lane;
    #pragma unroll
    for (int p = 0; p < 8; ++p) {
      va[p] = vp[(2 * p) * D_DIM];
      vb[p] = vp[(2 * p + 1) * D_DIM];
    }
  };

  // write-side swizzle constants
  const int prk   = kr >> 1;
  const int kbase = prk * 16 + ((kr & 1) << 3) + (kcc ^ (prk & 7));
  const int prv   = lane >> 1;
  const int swv   = prv & 7;
  const int vbase = prv * 16 + ((lane & 1) << 3);
  const int vc0   = vbase + ((2 * w) ^ swv);
  const int vc1   = vbase + ((2 * w + 1) ^ swv);

  auto WRITE = [&](int kb, int vbuf) {
    UH8 c0, c1;
    c0.w[0] = pkh(ka0.x, ka0.y); c0.w[1] = pkh(ka0.z, ka0.w);
    c0.w[2] = pkh(kb0.x, kb0.y); c0.w[3] = pkh(kb0.z, kb0.w);
    KsB[kb][kbase] = c0;
    c1.w[0] = pkh(ka1.x, ka1.y); c1.w[1] = pkh(ka1.z, ka1.w);
    c1.w[2] = pkh(kb1.x, kb1.y); c1.w[3] = pkh(kb1.z, kb1.w);
    KsB[kb][kbase + 256] = c1;
    UH8 d0, d1;
    #pragma unroll
    for (int j = 0; j < 4; ++j) {
      d0.w[j] = pkh(va[j], vb[j]);
      d1.w[j] = pkh(va[4 + j], vb[4 + j]);
    }
    VtB[vbuf][vc0] = d0;
    VtB[vbuf][vc1] = d1;
  };

  // read-side swizzle constants: row = (kvt|dt)*32 + q32, cc = 2s + h
  const int prq   = q32 >> 1;
  const int swq   = prq & 7;
  const int rbase = prq * 16 + ((q32 & 1) << 3);
  int eidx[4];
  #pragma unroll
  for (int s = 0; s < 4; ++s) eidx[s] = rbase + ((2 * s + h) ^ swq);

  // ---- Q fragments fp16, pre-scaled by LOG2E ----
  UH8 qf[4];
  {
    const float* qp = Q + base + (size_t)(q0 + w * 32 + q32) * D_DIM;
    #pragma unroll
    for (int s = 0; s < 4; ++s) {
      float4 a = *(const float4*)(qp + s * 16 + h * 8);
      float4 b = *(const float4*)(qp + s * 16 + h * 8 + 4);
      qf[s].w[0] = pkh(a.x * LOG2E, a.y * LOG2E);
      qf[s].w[1] = pkh(a.z * LOG2E, a.w * LOG2E);
      qf[s].w[2] = pkh(b.x * LOG2E, b.y * LOG2E);
      qf[s].w[3] = pkh(b.z * LOG2E, b.w * LOG2E);
    }
  }

  // O^T accum: oc[dt] reg r -> O[d = dt*32 + (r&3) + 8*(r>>2) + 4h][q = q32]
  f32x16 oc[2] = {
    {0,0,0,0,0,0,0,0,0,0,0,0,0,0,0,0},
    {0,0,0,0,0,0,0,0,0,0,0,0,0,0,0,0}
  };
  float mrow = -1e30f;   // running max in log2 units
  float lrow = 0.f;

  const U32H one = {0x3C003C00u};   // (1.0h, 1.0h)

  // QK^T for tile staged in ksc -> (s0, s1)
  auto QKT = [&](const UH8* ksc, f32x16& s0, f32x16& s1) {
    f32x16 a0 = {0,0,0,0,0,0,0,0,0,0,0,0,0,0,0,0};
    f32x16 a1 = {0,0,0,0,0,0,0,0,0,0,0,0,0,0,0,0};
    #pragma unroll
    for (int s = 0; s < 4; ++s)
      a0 = __builtin_amdgcn_mfma_f32_32x32x16_f16(ksc[eidx[s]].v, qf[s].v, a0, 0, 0, 0);
    #pragma unroll
    for (int s = 0; s < 4; ++s)
      a1 = __builtin_amdgcn_mfma_f32_32x32x16_f16(ksc[256 + eidx[s]].v, qf[s].v, a1, 0, 0, 0);
    s0 = a0;
    s1 = a1;
  };

  // softmax + PV for a finished score tile (s0, s1), V in vtc
  auto FINISH = [&](f32x16& s0, f32x16& s1, const UH8* vtc) {
    float u[8];
    #pragma unroll
    for (int j = 0; j < 8; ++j)
      u[j] = fmaxf(fmaxf(s0[j], s0[j + 8]), fmaxf(s1[j], s1[j + 8]));
    #pragma unroll
    for (int j = 0; j < 4; ++j) u[j] = fmaxf(u[j], u[j + 4]);
    float pm = fmaxf(fmaxf(u[0], u[2]), fmaxf(u[1], u[3]));
    pm = fmaxf(pm, __shfl_xor(pm, 32, 64));
    if (__any(pm - mrow > THR_L2)) {     // rare at THR=13
      const float mnew = fmaxf(mrow, pm);
      const float corr = __builtin_amdgcn_exp2f(mrow - mnew);
      #pragma unroll
      for (int dt = 0; dt < 2; ++dt)
        #pragma unroll
        for (int i = 0; i < 16; ++i)
          oc[dt][i] *= corr;
      lrow *= corr;
      mrow = mnew;
    }
    #pragma unroll
    for (int i = 0; i < 16; ++i) {
      s0[i] = __builtin_amdgcn_exp2f(s0[i] - mrow);
      s1[i] = __builtin_amdgcn_exp2f(s1[i] - mrow);
    }
    float ps = 0.f;
    auto PVS = [&](f32x16& sk, int sr, int ei) {
      unsigned int LO0 = pkh(sk[sr + 0], sk[sr + 1]);
      unsigned int LO1 = pkh(sk[sr + 2], sk[sr + 3]);
      unsigned int HI0 = pkh(sk[sr + 4], sk[sr + 5]);
      unsigned int HI1 = pkh(sk[sr + 6], sk[sr + 7]);
      U32H c0 = {LO0}, c1 = {LO1}, c2 = {HI0}, c3 = {HI1};
      ps = __builtin_amdgcn_fdot2(c0.h, one.h, ps, false);
      ps = __builtin_amdgcn_fdot2(c1.h, one.h, ps, false);
      ps = __builtin_amdgcn_fdot2(c2.h, one.h, ps, false);
      ps = __builtin_amdgcn_fdot2(c3.h, one.h, ps, false);
      // v_permlane32_swap_b32 vdst, vsrc: vdst HIGH 32 lanes <-> vsrc LOW 32 lanes
      asm("v_permlane32_swap_b32 %0, %1" : "+v"(LO0), "+v"(HI0));
      asm("v_permlane32_swap_b32 %0, %1" : "+v"(LO1), "+v"(HI1));
      UH8 pf;
      pf.w[0] = LO0;
      pf.w[1] = LO1;
      pf.w[2] = HI0;
      pf.w[3] = HI1;
      oc[0] = __builtin_amdgcn_mfma_f32_32x32x16_f16(vtc[ei].v, pf.v, oc[0], 0, 0, 0);
      oc[1] = __builtin_amdgcn_mfma_f32_32x32x16_f16(vtc[256 + ei].v, pf.v, oc[1], 0, 0, 0);
    };
    PVS(s0, 0, eidx[0]);
    PVS(s0, 8, eidx[1]);
    PVS(s1, 0, eidx[2]);
    PVS(s1, 8, eidx[3]);
    ps += __shfl_xor(ps, 32, 64);
    lrow += ps;
  };

  // ---- att[2] pipeline: QK^T(t) overlaps softmax+PV(t-1) ----
  f32x16 scA0, scA1, scB0, scB1;

  PREF(0);
  WRITE(0, 0);                 // tile 0 -> K[0], V[0]
  PREF(1);
  __syncthreads();
  QKT(KsB[0], scA0, scA1);     // tile 0 scores
  WRITE(1, 1);                 // tile 1 -> K[1], V[1]

  int vr = 0, vw = 2;          // vr = (t-1)%3, vw = (t+1)%3 at loop top (t=1)
  for (int tp = 1; tp + 1 < NT; tp += 2) {
    // ---- t = tp (odd): new scores -> B, finish tile t-1 from A ----
    __syncthreads();           // K[1],V[tp%3] staged by all
    PREF(tp + 1);
    QKT(KsB[1], scB0, scB1);           // MFMA chain, no dep on FINISH below
    FINISH(scA0, scA1, VtB[vr]);       // VALU chain, interleaves with QKT
    WRITE(0, vw);                      // tile tp+1
    vr = (vr == 2) ? 0 : vr + 1;
    vw = (vw == 2) ? 0 : vw + 1;
    // ---- t = tp+1 (even): new scores -> A, finish from B ----
    __syncthreads();
    const bool more2 = (tp + 2 < NT);
    if (more2) PREF(tp + 2);
    QKT(KsB[0], scA0, scA1);
    FINISH(scB0, scB1, VtB[vr]);
    if (more2) WRITE(1, vw);           // tile tp+2
    vr = (vr == 2) ? 0 : vr + 1;
    vw = (vw == 2) ? 0 : vw + 1;
  }
  // ---- t = NT-1 (odd): last QK^T, finish tile NT-2 ----
  __syncthreads();
  QKT(KsB[1], scB0, scB1);
  FINISH(scA0, scA1, VtB[vr]);         // tile NT-2, vr = (NT-2)%3 = 0
  // ---- epilogue: finish tile NT-1 ----
  FINISH(scB0, scB1, VtB[(NT - 1) % 3]);

  // ---- final stores: O[q][d] = oc * (dim^-0.25 / l) ----
  const float inv = INV_D_QTR / lrow;
  float* orow = O + base + (size_t)(q0 + w * 32 + q32) * D_DIM;
  #pragma unroll
  for (int dt = 0; dt < 2; ++dt)
    #pragma unroll
    for (int r1 = 0; r1 < 4; ++r1) {
      f32x4 o = { oc[dt][4 * r1 + 0] * inv, oc[dt][4 * r1 + 1] * inv,
                  oc[dt][4 * r1 + 2] * inv, oc[dt][4 * r1 + 3] * inv };
      *(f32x4*)(orow + dt * 32 + 8 * r1 + 4 * h) = o;
    }
}

extern "C" void kernel_launch(void* const* d_in, const int* in_sizes, int n_in,
                              void* d_out, int out_size, void* d_ws, size_t ws_size,
                              hipStream_t stream) {
  const float* q = (const float*)d_in[0];
  const float* k = (const float*)d_in[1];
  const float* v = (const float*)d_in[2];
  float* o = (float*)d_out;
  const int nblocks = (S_LEN / QB) * 64;   // 16 q-blocks x 64 bh = 1024
  attn_fwd<<<dim3(nblocks), dim3(256), 0, stream>>>(q, k, v, o);
}

// Round 12
// 130.707 us; speedup vs baseline: 2.0810x; 2.0810x over previous
//
#include <hip/hip_runtime.h>
#include <hip/hip_bf16.h>

typedef __attribute__((ext_vector_type(8))) _Float16 half8;
typedef __attribute__((ext_vector_type(2))) _Float16 hf2;
typedef __attribute__((ext_vector_type(2))) __fp16 fp16x2;
typedef __attribute__((ext_vector_type(4))) float f32x4;
typedef __attribute__((ext_vector_type(16))) float f32x16;

union UH8 {
  half8 v;
  unsigned long long q[2];
  unsigned int w[4];
};
union U32H {
  unsigned int u;
  hf2 h;
};

__device__ __forceinline__ unsigned int pkh(float lo, float hi) {
  union { fp16x2 h; unsigned int u; } c;
  c.h = __builtin_amdgcn_cvt_pkrtz(lo, hi);
  return c.u;
}

__device__ __forceinline__ void gload_lds16(const void* g, void* l) {
  __builtin_amdgcn_global_load_lds(
      (const __attribute__((address_space(1))) unsigned int*)g,
      (__attribute__((address_space(3))) unsigned int*)l, 16, 0, 0);
}

constexpr int S_LEN = 2048;
constexpr int D_DIM = 64;
constexpr int KVB   = 64;     // kv tile rows
constexpr int QB    = 128;    // q rows per block (4 waves x 32)
constexpr int NCHK  = 512;    // 16B chunks per 64x64 fp16 tile (8 KB)
constexpr int NT    = S_LEN / KVB;
constexpr int BH    = 64;
constexpr float LOG2E = 1.4426950408889634f;
constexpr float INV_D_QTR = 0.35355339059327373f;  // 1 / 64^0.25
constexpr float THR_L2 = 13.0f;  // defer-max: P <= 2^13, fp16-safe

// Swizzled tile layout (K and V^T), all LDS accesses ds_*_b128:
//   physical chunk = (row>>1)*16 + ((row&1)<<3) + (cc ^ ((row>>1)&7))
__device__ __forceinline__ int physchunk(int row, int cc) {
  return (row >> 1) * 16 + ((row & 1) << 3) + (cc ^ ((row >> 1) & 7));
}

// ---------------- prep: K/V fp32 -> fp16, pre-swizzled chunk layout ----------------
// KV16: [bh*32+t][512] K chunks, then same-size V^T block.
__global__ __launch_bounds__(256) void prep_kv(
    const float* __restrict__ K, const float* __restrict__ V, UH8* __restrict__ KV16)
{
  const int bt  = blockIdx.x;          // bh*32 + t
  const int tid = threadIdx.x;
  const size_t base = (size_t)(bt >> 5) * S_LEN * D_DIM + (size_t)(bt & 31) * KVB * D_DIM;
  UH8* kdst = KV16 + (size_t)bt * NCHK;
  UH8* vdst = KV16 + (size_t)(BH * 32) * NCHK + (size_t)bt * NCHK;

  // K: 2 chunks per thread (logical r = c>>3, cc = c&7)
  #pragma unroll
  for (int i = 0; i < 2; ++i) {
    const int c = tid + 256 * i;
    const int r = c >> 3, cc = c & 7;
    const float* kp = K + base + (size_t)r * D_DIM + cc * 8;
    float4 a = *(const float4*)kp;
    float4 b = *(const float4*)(kp + 4);
    UH8 ch;
    ch.w[0] = pkh(a.x, a.y); ch.w[1] = pkh(a.z, a.w);
    ch.w[2] = pkh(b.x, b.y); ch.w[3] = pkh(b.z, b.w);
    kdst[physchunk(r, cc)] = ch;
  }
  // V^T: chunk (row=d, cc) holds V[cc*8+j][d], j=0..7
  const int d   = tid & 63;
  const int ccq = tid >> 6;
  #pragma unroll
  for (int i = 0; i < 2; ++i) {
    const int cc = 2 * ccq + i;
    UH8 ch;
    #pragma unroll
    for (int j = 0; j < 4; ++j) {
      const float x0 = V[base + (size_t)(cc * 8 + 2 * j) * D_DIM + d];
      const float x1 = V[base + (size_t)(cc * 8 + 2 * j + 1) * D_DIM + d];
      ch.w[j] = pkh(x0, x1);
    }
    vdst[physchunk(d, cc)] = ch;
  }
}

// ---------------- attention: gload_lds staging, fp16 MFMA ----------------
__global__ __launch_bounds__(256) void attn_fwd2(
    const float* __restrict__ Q, const UH8* __restrict__ KV16, float* __restrict__ O)
{
  const int tid  = threadIdx.x;
  const int w    = tid >> 6;
  const int lane = tid & 63;
  const int q32  = lane & 31;
  const int h    = lane >> 5;

  // XCD-aware bijective swizzle (1024 = 8 x 128)
  const int bid = blockIdx.x;
  const int wg  = (bid & 7) * 128 + (bid >> 3);
  const int qb  = wg & 15;
  const int bh  = wg >> 4;
  const int q0  = qb * QB;

  __shared__ UH8 KsB[2][NCHK];
  __shared__ UH8 VtB[2][NCHK];

  const size_t base = (size_t)bh * S_LEN * D_DIM;
  const UH8* k16 = KV16 + (size_t)bh * 32 * NCHK;
  const UH8* v16 = KV16 + (size_t)(BH * 32) * NCHK + (size_t)bh * 32 * NCHK;

  auto STAGE = [&](int t, int b) {
    const UH8* ks = k16 + (size_t)t * NCHK + w * 128 + lane;   // per-lane global src
    const UH8* vs = v16 + (size_t)t * NCHK + w * 128 + lane;
    gload_lds16(ks,      &KsB[b][w * 128]);        // lds dst wave-uniform
    gload_lds16(ks + 64, &KsB[b][w * 128 + 64]);
    gload_lds16(vs,      &VtB[b][w * 128]);
    gload_lds16(vs + 64, &VtB[b][w * 128 + 64]);
  };

  // read-side swizzle: row = (kvt|dt)*32 + q32, cc = 2s + h
  const int prq   = q32 >> 1;
  const int swq   = prq & 7;
  const int rbase = prq * 16 + ((q32 & 1) << 3);
  int eidx[4];
  #pragma unroll
  for (int s = 0; s < 4; ++s) eidx[s] = rbase + ((2 * s + h) ^ swq);

  STAGE(0, 0);

  // Q fragments fp16, pre-scaled by LOG2E
  UH8 qf[4];
  {
    const float* qp = Q + base + (size_t)(q0 + w * 32 + q32) * D_DIM;
    #pragma unroll
    for (int s = 0; s < 4; ++s) {
      float4 a = *(const float4*)(qp + s * 16 + h * 8);
      float4 b = *(const float4*)(qp + s * 16 + h * 8 + 4);
      qf[s].w[0] = pkh(a.x * LOG2E, a.y * LOG2E);
      qf[s].w[1] = pkh(a.z * LOG2E, a.w * LOG2E);
      qf[s].w[2] = pkh(b.x * LOG2E, b.y * LOG2E);
      qf[s].w[3] = pkh(b.z * LOG2E, b.w * LOG2E);
    }
  }

  f32x16 oc[2] = {
    {0,0,0,0,0,0,0,0,0,0,0,0,0,0,0,0},
    {0,0,0,0,0,0,0,0,0,0,0,0,0,0,0,0}
  };
  float mrow = -1e30f;
  float lrow = 0.f;
  const U32H one = {0x3C003C00u};

  for (int t = 0; t < NT; ++t) {
    __syncthreads();                       // buf[t&1] staged (drain), prior reads done
    if (t + 1 < NT) STAGE(t + 1, (t + 1) & 1);
    const UH8* ksc = KsB[t & 1];
    const UH8* vtc = VtB[t & 1];

    // swapped QK^T (32x32x16)
    f32x16 sc0, sc1;
    __builtin_amdgcn_s_setprio(1);
    {
      f32x16 a0 = {0,0,0,0,0,0,0,0,0,0,0,0,0,0,0,0};
      f32x16 a1 = {0,0,0,0,0,0,0,0,0,0,0,0,0,0,0,0};
      #pragma unroll
      for (int s = 0; s < 4; ++s)
        a0 = __builtin_amdgcn_mfma_f32_32x32x16_f16(ksc[eidx[s]].v, qf[s].v, a0, 0, 0, 0);
      #pragma unroll
      for (int s = 0; s < 4; ++s)
        a1 = __builtin_amdgcn_mfma_f32_32x32x16_f16(ksc[256 + eidx[s]].v, qf[s].v, a1, 0, 0, 0);
      sc0 = a0; sc1 = a1;
    }
    __builtin_amdgcn_s_setprio(0);

    // tile max, tree-form
    float u[8];
    #pragma unroll
    for (int j = 0; j < 8; ++j)
      u[j] = fmaxf(fmaxf(sc0[j], sc0[j + 8]), fmaxf(sc1[j], sc1[j + 8]));
    #pragma unroll
    for (int j = 0; j < 4; ++j) u[j] = fmaxf(u[j], u[j + 4]);
    float pm = fmaxf(fmaxf(u[0], u[2]), fmaxf(u[1], u[3]));
    pm = fmaxf(pm, __shfl_xor(pm, 32, 64));

    if (__any(pm - mrow > THR_L2)) {
      const float mnew = fmaxf(mrow, pm);
      const float corr = __builtin_amdgcn_exp2f(mrow - mnew);
      #pragma unroll
      for (int dt = 0; dt < 2; ++dt)
        #pragma unroll
        for (int i = 0; i < 16; ++i)
          oc[dt][i] *= corr;
      lrow *= corr;
      mrow = mnew;
    }

    #pragma unroll
    for (int i = 0; i < 16; ++i) {
      sc0[i] = __builtin_amdgcn_exp2f(sc0[i] - mrow);
      sc1[i] = __builtin_amdgcn_exp2f(sc1[i] - mrow);
    }

    // swapped PV + row-sum via fdot2
    float ps = 0.f;
    __builtin_amdgcn_s_setprio(1);
    #pragma unroll
    for (int s = 0; s < 4; ++s) {
      const f32x16& sk = (s < 2) ? sc0 : sc1;
      const int sr = (s & 1) * 8;
      unsigned int LO0 = pkh(sk[sr + 0], sk[sr + 1]);
      unsigned int LO1 = pkh(sk[sr + 2], sk[sr + 3]);
      unsigned int HI0 = pkh(sk[sr + 4], sk[sr + 5]);
      unsigned int HI1 = pkh(sk[sr + 6], sk[sr + 7]);
      U32H c0 = {LO0}, c1 = {LO1}, c2 = {HI0}, c3 = {HI1};
      ps = __builtin_amdgcn_fdot2(c0.h, one.h, ps, false);
      ps = __builtin_amdgcn_fdot2(c1.h, one.h, ps, false);
      ps = __builtin_amdgcn_fdot2(c2.h, one.h, ps, false);
      ps = __builtin_amdgcn_fdot2(c3.h, one.h, ps, false);
      asm("v_permlane32_swap_b32 %0, %1" : "+v"(LO0), "+v"(HI0));
      asm("v_permlane32_swap_b32 %0, %1" : "+v"(LO1), "+v"(HI1));
      UH8 pf;
      pf.w[0] = LO0; pf.w[1] = LO1; pf.w[2] = HI0; pf.w[3] = HI1;
      oc[0] = __builtin_amdgcn_mfma_f32_32x32x16_f16(vtc[eidx[s]].v, pf.v, oc[0], 0, 0, 0);
      oc[1] = __builtin_amdgcn_mfma_f32_32x32x16_f16(vtc[256 + eidx[s]].v, pf.v, oc[1], 0, 0, 0);
    }
    __builtin_amdgcn_s_setprio(0);
    ps += __shfl_xor(ps, 32, 64);
    lrow += ps;
  }

  const float inv = INV_D_QTR / lrow;
  float* orow = O + base + (size_t)(q0 + w * 32 + q32) * D_DIM;
  #pragma unroll
  for (int dt = 0; dt < 2; ++dt)
    #pragma unroll
    for (int r1 = 0; r1 < 4; ++r1) {
      f32x4 o = { oc[dt][4 * r1 + 0] * inv, oc[dt][4 * r1 + 1] * inv,
                  oc[dt][4 * r1 + 2] * inv, oc[dt][4 * r1 + 3] * inv };
      *(f32x4*)(orow + dt * 32 + 8 * r1 + 4 * h) = o;
    }
}

// ---------------- fallback (r10 kernel, known-good) if ws too small ----------------
__global__ __launch_bounds__(256) void attn_fwd_fb(
    const float* __restrict__ Q, const float* __restrict__ K,
    const float* __restrict__ V, float* __restrict__ O)
{
  const int tid  = threadIdx.x;
  const int w    = tid >> 6;
  const int lane = tid & 63;
  const int q32  = lane & 31;
  const int h    = lane >> 5;
  const int bid = blockIdx.x;
  const int wg  = (bid & 7) * 128 + (bid >> 3);
  const int qb  = wg & 15;
  const int bh  = wg >> 4;
  const int q0 = qb * QB;
  __shared__ UH8 KsB[2][NCHK];
  __shared__ UH8 VtB[2][NCHK];
  const size_t base = (size_t)bh * S_LEN * D_DIM;
  const int kr  = tid >> 3;
  const int kcc = tid & 7;
  float4 ka0, kb0, ka1, kb1;
  float va[8], vb[8];
  auto PREF = [&](int tt) {
    const int kv0 = tt * KVB;
    const float* kp = K + base + (size_t)(kv0 + kr) * D_DIM + kcc * 8;
    ka0 = *(const float4*)kp;
    kb0 = *(const float4*)(kp + 4);
    const float* kp1 = kp + 32 * D_DIM;
    ka1 = *(const float4*)kp1;
    kb1 = *(const float4*)(kp1 + 4);
    const float* vp = V + base + (size_t)(kv0 + w * 16) * D_DIM + lane;
    #pragma unroll
    for (int p = 0; p < 8; ++p) {
      va[p] = vp[(2 * p) * D_DIM];
      vb[p] = vp[(2 * p + 1) * D_DIM];
    }
  };
  const int prk   = kr >> 1;
  const int kbase = prk * 16 + ((kr & 1) << 3) + (kcc ^ (prk & 7));
  const int prv   = lane >> 1;
  const int swv   = prv & 7;
  const int vbase = prv * 16 + ((lane & 1) << 3);
  const int vc0   = vbase + ((2 * w) ^ swv);
  const int vc1   = vbase + ((2 * w + 1) ^ swv);
  auto WRITE = [&](int b) {
    UH8 c0, c1;
    c0.w[0] = pkh(ka0.x, ka0.y); c0.w[1] = pkh(ka0.z, ka0.w);
    c0.w[2] = pkh(kb0.x, kb0.y); c0.w[3] = pkh(kb0.z, kb0.w);
    KsB[b][kbase] = c0;
    c1.w[0] = pkh(ka1.x, ka1.y); c1.w[1] = pkh(ka1.z, ka1.w);
    c1.w[2] = pkh(kb1.x, kb1.y); c1.w[3] = pkh(kb1.z, kb1.w);
    KsB[b][kbase + 256] = c1;
    UH8 d0, d1;
    #pragma unroll
    for (int j = 0; j < 4; ++j) {
      d0.w[j] = pkh(va[j], vb[j]);
      d1.w[j] = pkh(va[4 + j], vb[4 + j]);
    }
    VtB[b][vc0] = d0;
    VtB[b][vc1] = d1;
  };
  const int prq   = q32 >> 1;
  const int swq   = prq & 7;
  const int rbase = prq * 16 + ((q32 & 1) << 3);
  int eidx[4];
  #pragma unroll
  for (int s = 0; s < 4; ++s) eidx[s] = rbase + ((2 * s + h) ^ swq);
  UH8 qf[4];
  {
    const float* qp = Q + base + (size_t)(q0 + w * 32 + q32) * D_DIM;
    #pragma unroll
    for (int s = 0; s < 4; ++s) {
      float4 a = *(const float4*)(qp + s * 16 + h * 8);
      float4 b = *(const float4*)(qp + s * 16 + h * 8 + 4);
      qf[s].w[0] = pkh(a.x * LOG2E, a.y * LOG2E);
      qf[s].w[1] = pkh(a.z * LOG2E, a.w * LOG2E);
      qf[s].w[2] = pkh(b.x * LOG2E, b.y * LOG2E);
      qf[s].w[3] = pkh(b.z * LOG2E, b.w * LOG2E);
    }
  }
  f32x16 oc[2] = {
    {0,0,0,0,0,0,0,0,0,0,0,0,0,0,0,0},
    {0,0,0,0,0,0,0,0,0,0,0,0,0,0,0,0}
  };
  float mrow = -1e30f;
  float lrow = 0.f;
  const U32H one = {0x3C003C00u};
  PREF(0);
  WRITE(0);
  for (int t = 0; t < NT; ++t) {
    const bool more = (t + 1 < NT);
    if (more) PREF(t + 1);
    __syncthreads();
    const int cb = t & 1;
    const UH8* ksc = KsB[cb];
    const UH8* vtc = VtB[cb];
    f32x16 sc[2];
    __builtin_amdgcn_s_setprio(1);
    #pragma unroll
    for (int kvt = 0; kvt < 2; ++kvt) {
      f32x16 acc = {0,0,0,0,0,0,0,0,0,0,0,0,0,0,0,0};
      #pragma unroll
      for (int s = 0; s < 4; ++s) {
        UH8 af;
        af.v = ksc[kvt * 256 + eidx[s]].v;
        acc = __builtin_amdgcn_mfma_f32_32x32x16_f16(af.v, qf[s].v, acc, 0, 0, 0);
      }
      sc[kvt] = acc;
    }
    __builtin_amdgcn_s_setprio(0);
    float u[8];
    #pragma unroll
    for (int j = 0; j < 8; ++j)
      u[j] = fmaxf(fmaxf(sc[0][j], sc[0][j + 8]), fmaxf(sc[1][j], sc[1][j + 8]));
    #pragma unroll
    for (int j = 0; j < 4; ++j) u[j] = fmaxf(u[j], u[j + 4]);
    float pm = fmaxf(fmaxf(u[0], u[2]), fmaxf(u[1], u[3]));
    pm = fmaxf(pm, __shfl_xor(pm, 32, 64));
    if (__any(pm - mrow > THR_L2)) {
      const float mnew = fmaxf(mrow, pm);
      const float corr = __builtin_amdgcn_exp2f(mrow - mnew);
      #pragma unroll
      for (int dt = 0; dt < 2; ++dt)
        #pragma unroll
        for (int i = 0; i < 16; ++i)
          oc[dt][i] *= corr;
      lrow *= corr;
      mrow = mnew;
    }
    #pragma unroll
    for (int kvt = 0; kvt < 2; ++kvt)
      #pragma unroll
      for (int i = 0; i < 16; ++i)
        sc[kvt][i] = __builtin_amdgcn_exp2f(sc[kvt][i] - mrow);
    float ps = 0.f;
    __builtin_amdgcn_s_setprio(1);
    #pragma unroll
    for (int s = 0; s < 4; ++s) {
      const int kvt = s >> 1;
      const int sr  = (s & 1) * 8;
      unsigned int LO0 = pkh(sc[kvt][sr + 0], sc[kvt][sr + 1]);
      unsigned int LO1 = pkh(sc[kvt][sr + 2], sc[kvt][sr + 3]);
      unsigned int HI0 = pkh(sc[kvt][sr + 4], sc[kvt][sr + 5]);
      unsigned int HI1 = pkh(sc[kvt][sr + 6], sc[kvt][sr + 7]);
      U32H c0 = {LO0}, c1 = {LO1}, c2 = {HI0}, c3 = {HI1};
      ps = __builtin_amdgcn_fdot2(c0.h, one.h, ps, false);
      ps = __builtin_amdgcn_fdot2(c1.h, one.h, ps, false);
      ps = __builtin_amdgcn_fdot2(c2.h, one.h, ps, false);
      ps = __builtin_amdgcn_fdot2(c3.h, one.h, ps, false);
      asm("v_permlane32_swap_b32 %0, %1" : "+v"(LO0), "+v"(HI0));
      asm("v_permlane32_swap_b32 %0, %1" : "+v"(LO1), "+v"(HI1));
      UH8 pf;
      pf.w[0] = LO0; pf.w[1] = LO1; pf.w[2] = HI0; pf.w[3] = HI1;
      #pragma unroll
      for (int dt = 0; dt < 2; ++dt) {
        UH8 vf;
        vf.v = vtc[dt * 256 + eidx[s]].v;
        oc[dt] = __builtin_amdgcn_mfma_f32_32x32x16_f16(vf.v, pf.v, oc[dt], 0, 0, 0);
      }
    }
    __builtin_amdgcn_s_setprio(0);
    ps += __shfl_xor(ps, 32, 64);
    lrow += ps;
    if (more) WRITE(1 - cb);
  }
  const float inv = INV_D_QTR / lrow;
  float* orow = O + base + (size_t)(q0 + w * 32 + q32) * D_DIM;
  #pragma unroll
  for (int dt = 0; dt < 2; ++dt)
    #pragma unroll
    for (int r1 = 0; r1 < 4; ++r1) {
      f32x4 o = { oc[dt][4 * r1 + 0] * inv, oc[dt][4 * r1 + 1] * inv,
                  oc[dt][4 * r1 + 2] * inv, oc[dt][4 * r1 + 3] * inv };
      *(f32x4*)(orow + dt * 32 + 8 * r1 + 4 * h) = o;
    }
}

extern "C" void kernel_launch(void* const* d_in, const int* in_sizes, int n_in,
                              void* d_out, int out_size, void* d_ws, size_t ws_size,
                              hipStream_t stream) {
  const float* q = (const float*)d_in[0];
  const float* k = (const float*)d_in[1];
  const float* v = (const float*)d_in[2];
  float* o = (float*)d_out;
  const size_t need = 2ull * BH * 32 * NCHK * sizeof(UH8);   // 33.6 MB
  if (ws_size >= need) {
    prep_kv<<<dim3(BH * 32), dim3(256), 0, stream>>>(k, v, (UH8*)d_ws);
    attn_fwd2<<<dim3(1024), dim3(256), 0, stream>>>(q, (const UH8*)d_ws, o);
  } else {
    attn_fwd_fb<<<dim3(1024), dim3(256), 0, stream>>>(q, k, v, o);
  }
}

// Round 13
// 126.739 us; speedup vs baseline: 2.1462x; 1.0313x over previous
//
#include <hip/hip_runtime.h>
#include <hip/hip_bf16.h>

typedef __attribute__((ext_vector_type(8))) _Float16 half8;
typedef __attribute__((ext_vector_type(2))) _Float16 hf2;
typedef __attribute__((ext_vector_type(2))) __fp16 fp16x2;
typedef __attribute__((ext_vector_type(4))) float f32x4;
typedef __attribute__((ext_vector_type(16))) float f32x16;

union UH8 {
  half8 v;
  unsigned long long q[2];
  unsigned int w[4];
};
union U32H {
  unsigned int u;
  hf2 h;
};

__device__ __forceinline__ unsigned int pkh(float lo, float hi) {
  union { fp16x2 h; unsigned int u; } c;
  c.h = __builtin_amdgcn_cvt_pkrtz(lo, hi);
  return c.u;
}

__device__ __forceinline__ void gload_lds16(const void* g, void* l) {
  __builtin_amdgcn_global_load_lds(
      (const __attribute__((address_space(1))) unsigned int*)g,
      (__attribute__((address_space(3))) unsigned int*)l, 16, 0, 0);
}

constexpr int S_LEN = 2048;
constexpr int D_DIM = 64;
constexpr int KVB   = 64;
constexpr int QB    = 128;
constexpr int NCHK  = 512;    // 16B chunks per 64x64 fp16 tile (8 KB)
constexpr int NT    = S_LEN / KVB;   // 32
constexpr int BH    = 64;
constexpr float LOG2E = 1.4426950408889634f;
constexpr float INV_D_QTR = 0.35355339059327373f;  // 1 / 64^0.25
constexpr float THR_L2 = 13.0f;  // defer-max: P <= 2^13, fp16-safe

// Swizzled tile layout (K and V^T), all LDS accesses ds_*_b128:
//   physical chunk = (row>>1)*16 + ((row&1)<<3) + (cc ^ ((row>>1)&7))
__device__ __forceinline__ int physchunk(int row, int cc) {
  return (row >> 1) * 16 + ((row & 1) << 3) + (cc ^ ((row >> 1) & 7));
}

// ---------------- prep: K/V fp32 -> fp16, pre-swizzled chunk layout ----------------
__global__ __launch_bounds__(256) void prep_kv(
    const float* __restrict__ K, const float* __restrict__ V, UH8* __restrict__ KV16)
{
  const int bt  = blockIdx.x;          // bh*32 + t
  const int tid = threadIdx.x;
  const size_t base = (size_t)(bt >> 5) * S_LEN * D_DIM + (size_t)(bt & 31) * KVB * D_DIM;
  UH8* kdst = KV16 + (size_t)bt * NCHK;
  UH8* vdst = KV16 + (size_t)(BH * 32) * NCHK + (size_t)bt * NCHK;

  #pragma unroll
  for (int i = 0; i < 2; ++i) {
    const int c = tid + 256 * i;
    const int r = c >> 3, cc = c & 7;
    const float* kp = K + base + (size_t)r * D_DIM + cc * 8;
    float4 a = *(const float4*)kp;
    float4 b = *(const float4*)(kp + 4);
    UH8 ch;
    ch.w[0] = pkh(a.x, a.y); ch.w[1] = pkh(a.z, a.w);
    ch.w[2] = pkh(b.x, b.y); ch.w[3] = pkh(b.z, b.w);
    kdst[physchunk(r, cc)] = ch;
  }
  const int d   = tid & 63;
  const int ccq = tid >> 6;
  #pragma unroll
  for (int i = 0; i < 2; ++i) {
    const int cc = 2 * ccq + i;
    UH8 ch;
    #pragma unroll
    for (int j = 0; j < 4; ++j) {
      const float x0 = V[base + (size_t)(cc * 8 + 2 * j) * D_DIM + d];
      const float x1 = V[base + (size_t)(cc * 8 + 2 * j + 1) * D_DIM + d];
      ch.w[j] = pkh(x0, x1);
    }
    vdst[physchunk(d, cc)] = ch;
  }
}

// ---------------- attention: gload_lds staging + lagged-PV (T15-lite) ----------------
__global__ __launch_bounds__(256) void attn_fwd2(
    const float* __restrict__ Q, const UH8* __restrict__ KV16, float* __restrict__ O)
{
  const int tid  = threadIdx.x;
  const int w    = tid >> 6;
  const int lane = tid & 63;
  const int q32  = lane & 31;
  const int h    = lane >> 5;

  const int bid = blockIdx.x;
  const int wg  = (bid & 7) * 128 + (bid >> 3);
  const int qb  = wg & 15;
  const int bh  = wg >> 4;
  const int q0  = qb * QB;

  __shared__ UH8 KsB[2][NCHK];   // 16 KB
  __shared__ UH8 VtB[3][NCHK];   // 24 KB  (PV reads one tile late -> triple buffer)

  const size_t base = (size_t)bh * S_LEN * D_DIM;
  const UH8* k16 = KV16 + (size_t)bh * 32 * NCHK;
  const UH8* v16 = KV16 + (size_t)(BH * 32) * NCHK + (size_t)bh * 32 * NCHK;

  auto STAGE = [&](int t) {
    const UH8* ks = k16 + (size_t)t * NCHK + w * 128 + lane;
    const UH8* vs = v16 + (size_t)t * NCHK + w * 128 + lane;
    UH8* kb = &KsB[t & 1][w * 128];
    UH8* vb = &VtB[t % 3][w * 128];
    gload_lds16(ks,      kb);
    gload_lds16(ks + 64, kb + 64);
    gload_lds16(vs,      vb);
    gload_lds16(vs + 64, vb + 64);
  };

  // read-side swizzle: row = (kvt|dt)*32 + q32, cc = 2s + h
  const int prq   = q32 >> 1;
  const int swq   = prq & 7;
  const int rbase = prq * 16 + ((q32 & 1) << 3);
  int eidx[4];
  #pragma unroll
  for (int s = 0; s < 4; ++s) eidx[s] = rbase + ((2 * s + h) ^ swq);

  STAGE(0);

  UH8 qf[4];
  {
    const float* qp = Q + base + (size_t)(q0 + w * 32 + q32) * D_DIM;
    #pragma unroll
    for (int s = 0; s < 4; ++s) {
      float4 a = *(const float4*)(qp + s * 16 + h * 8);
      float4 b = *(const float4*)(qp + s * 16 + h * 8 + 4);
      qf[s].w[0] = pkh(a.x * LOG2E, a.y * LOG2E);
      qf[s].w[1] = pkh(a.z * LOG2E, a.w * LOG2E);
      qf[s].w[2] = pkh(b.x * LOG2E, b.y * LOG2E);
      qf[s].w[3] = pkh(b.z * LOG2E, b.w * LOG2E);
    }
  }

  f32x16 oc[2] = {
    {0,0,0,0,0,0,0,0,0,0,0,0,0,0,0,0},
    {0,0,0,0,0,0,0,0,0,0,0,0,0,0,0,0}
  };
  float mrow = -1e30f;
  float lrow = 0.f;
  const U32H one = {0x3C003C00u};

  // QK^T + softmax + pack: produces the packed P^T fragments for tile t.
  // Also performs the (rare) deferred rescale of oc/lrow — ordered after the
  // lagged PV via the oc register dependency.
  auto QKT_SM = [&](const UH8* ksc, UH8 (&pf)[4]) {
    f32x16 sc0 = {0,0,0,0,0,0,0,0,0,0,0,0,0,0,0,0};
    f32x16 sc1 = {0,0,0,0,0,0,0,0,0,0,0,0,0,0,0,0};
    #pragma unroll
    for (int s = 0; s < 4; ++s)
      sc0 = __builtin_amdgcn_mfma_f32_32x32x16_f16(ksc[eidx[s]].v, qf[s].v, sc0, 0, 0, 0);
    #pragma unroll
    for (int s = 0; s < 4; ++s)
      sc1 = __builtin_amdgcn_mfma_f32_32x32x16_f16(ksc[256 + eidx[s]].v, qf[s].v, sc1, 0, 0, 0);

    float u[8];
    #pragma unroll
    for (int j = 0; j < 8; ++j)
      u[j] = fmaxf(fmaxf(sc0[j], sc0[j + 8]), fmaxf(sc1[j], sc1[j + 8]));
    #pragma unroll
    for (int j = 0; j < 4; ++j) u[j] = fmaxf(u[j], u[j + 4]);
    float pm = fmaxf(fmaxf(u[0], u[2]), fmaxf(u[1], u[3]));
    pm = fmaxf(pm, __shfl_xor(pm, 32, 64));

    if (__any(pm - mrow > THR_L2)) {
      const float mnew = fmaxf(mrow, pm);
      const float corr = __builtin_amdgcn_exp2f(mrow - mnew);
      #pragma unroll
      for (int dt = 0; dt < 2; ++dt)
        #pragma unroll
        for (int i = 0; i < 16; ++i)
          oc[dt][i] *= corr;
      lrow *= corr;
      mrow = mnew;
    }

    #pragma unroll
    for (int i = 0; i < 16; ++i) {
      sc0[i] = __builtin_amdgcn_exp2f(sc0[i] - mrow);
      sc1[i] = __builtin_amdgcn_exp2f(sc1[i] - mrow);
    }

    float ps = 0.f;
    #pragma unroll
    for (int s = 0; s < 4; ++s) {
      const f32x16& sk = (s < 2) ? sc0 : sc1;
      const int sr = (s & 1) * 8;
      unsigned int LO0 = pkh(sk[sr + 0], sk[sr + 1]);
      unsigned int LO1 = pkh(sk[sr + 2], sk[sr + 3]);
      unsigned int HI0 = pkh(sk[sr + 4], sk[sr + 5]);
      unsigned int HI1 = pkh(sk[sr + 6], sk[sr + 7]);
      U32H c0 = {LO0}, c1 = {LO1}, c2 = {HI0}, c3 = {HI1};
      ps = __builtin_amdgcn_fdot2(c0.h, one.h, ps, false);
      ps = __builtin_amdgcn_fdot2(c1.h, one.h, ps, false);
      ps = __builtin_amdgcn_fdot2(c2.h, one.h, ps, false);
      ps = __builtin_amdgcn_fdot2(c3.h, one.h, ps, false);
      // vdst HIGH 32 lanes <-> vsrc LOW 32 lanes
      asm("v_permlane32_swap_b32 %0, %1" : "+v"(LO0), "+v"(HI0));
      asm("v_permlane32_swap_b32 %0, %1" : "+v"(LO1), "+v"(HI1));
      pf[s].w[0] = LO0; pf[s].w[1] = LO1; pf[s].w[2] = HI0; pf[s].w[3] = HI1;
    }
    ps += __shfl_xor(ps, 32, 64);
    lrow += ps;
  };

  // lagged PV: no data dependency on the QKT_SM that follows it in the same phase
  auto PV = [&](const UH8* vtc, UH8 (&pf)[4]) {
    #pragma unroll
    for (int s = 0; s < 4; ++s) {
      oc[0] = __builtin_amdgcn_mfma_f32_32x32x16_f16(vtc[eidx[s]].v, pf[s].v, oc[0], 0, 0, 0);
      oc[1] = __builtin_amdgcn_mfma_f32_32x32x16_f16(vtc[256 + eidx[s]].v, pf[s].v, oc[1], 0, 0, 0);
    }
  };

  UH8 pfA[4], pfB[4];

  // prologue: tile 0
  __syncthreads();                 // STAGE(0) drained
  STAGE(1);
  QKT_SM(KsB[0], pfA);             // pfA = tile 0

  // pairs: t = 1,3,...,29  (handles tiles 1..30)
  for (int t = 1; t <= NT - 3; t += 2) {
    __syncthreads();               // STAGE(t) drained; prior reads done
    STAGE(t + 1);
    PV(VtB[(t - 1) % 3], pfA);     // PV(t-1) — overlaps QKT_SM(t) below
    QKT_SM(KsB[t & 1], pfB);       // pfB = tile t
    __syncthreads();
    STAGE(t + 2);
    PV(VtB[t % 3], pfB);           // PV(t)
    QKT_SM(KsB[(t + 1) & 1], pfA); // pfA = tile t+1
  }

  // tail: tile NT-1
  __syncthreads();                 // STAGE(NT-1) drained
  PV(VtB[(NT - 2) % 3], pfA);      // PV(NT-2)
  QKT_SM(KsB[(NT - 1) & 1], pfB);  // scores for tile NT-1
  PV(VtB[(NT - 1) % 3], pfB);      // flush PV(NT-1)

  const float inv = INV_D_QTR / lrow;
  float* orow = O + base + (size_t)(q0 + w * 32 + q32) * D_DIM;
  #pragma unroll
  for (int dt = 0; dt < 2; ++dt)
    #pragma unroll
    for (int r1 = 0; r1 < 4; ++r1) {
      f32x4 o = { oc[dt][4 * r1 + 0] * inv, oc[dt][4 * r1 + 1] * inv,
                  oc[dt][4 * r1 + 2] * inv, oc[dt][4 * r1 + 3] * inv };
      *(f32x4*)(orow + dt * 32 + 8 * r1 + 4 * h) = o;
    }
}

// ---------------- fallback (r10 kernel, known-good) if ws too small ----------------
__global__ __launch_bounds__(256) void attn_fwd_fb(
    const float* __restrict__ Q, const float* __restrict__ K,
    const float* __restrict__ V, float* __restrict__ O)
{
  const int tid  = threadIdx.x;
  const int w    = tid >> 6;
  const int lane = tid & 63;
  const int q32  = lane & 31;
  const int h    = lane >> 5;
  const int bid = blockIdx.x;
  const int wg  = (bid & 7) * 128 + (bid >> 3);
  const int qb  = wg & 15;
  const int bh  = wg >> 4;
  const int q0 = qb * QB;
  __shared__ UH8 KsB[2][NCHK];
  __shared__ UH8 VtB[2][NCHK];
  const size_t base = (size_t)bh * S_LEN * D_DIM;
  const int kr  = tid >> 3;
  const int kcc = tid & 7;
  float4 ka0, kb0, ka1, kb1;
  float va[8], vb[8];
  auto PREF = [&](int tt) {
    const int kv0 = tt * KVB;
    const float* kp = K + base + (size_t)(kv0 + kr) * D_DIM + kcc * 8;
    ka0 = *(const float4*)kp;
    kb0 = *(const float4*)(kp + 4);
    const float* kp1 = kp + 32 * D_DIM;
    ka1 = *(const float4*)kp1;
    kb1 = *(const float4*)(kp1 + 4);
    const float* vp = V + base + (size_t)(kv0 + w * 16) * D_DIM + lane;
    #pragma unroll
    for (int p = 0; p < 8; ++p) {
      va[p] = vp[(2 * p) * D_DIM];
      vb[p] = vp[(2 * p + 1) * D_DIM];
    }
  };
  const int prk   = kr >> 1;
  const int kbase = prk * 16 + ((kr & 1) << 3) + (kcc ^ (prk & 7));
  const int prv   = lane >> 1;
  const int swv   = prv & 7;
  const int vbase = prv * 16 + ((lane & 1) << 3);
  const int vc0   = vbase + ((2 * w) ^ swv);
  const int vc1   = vbase + ((2 * w + 1) ^ swv);
  auto WRITE = [&](int b) {
    UH8 c0, c1;
    c0.w[0] = pkh(ka0.x, ka0.y); c0.w[1] = pkh(ka0.z, ka0.w);
    c0.w[2] = pkh(kb0.x, kb0.y); c0.w[3] = pkh(kb0.z, kb0.w);
    KsB[b][kbase] = c0;
    c1.w[0] = pkh(ka1.x, ka1.y); c1.w[1] = pkh(ka1.z, ka1.w);
    c1.w[2] = pkh(kb1.x, kb1.y); c1.w[3] = pkh(kb1.z, kb1.w);
    KsB[b][kbase + 256] = c1;
    UH8 d0, d1;
    #pragma unroll
    for (int j = 0; j < 4; ++j) {
      d0.w[j] = pkh(va[j], vb[j]);
      d1.w[j] = pkh(va[4 + j], vb[4 + j]);
    }
    VtB[b][vc0] = d0;
    VtB[b][vc1] = d1;
  };
  const int prq   = q32 >> 1;
  const int swq   = prq & 7;
  const int rbase = prq * 16 + ((q32 & 1) << 3);
  int eidx[4];
  #pragma unroll
  for (int s = 0; s < 4; ++s) eidx[s] = rbase + ((2 * s + h) ^ swq);
  UH8 qf[4];
  {
    const float* qp = Q + base + (size_t)(q0 + w * 32 + q32) * D_DIM;
    #pragma unroll
    for (int s = 0; s < 4; ++s) {
      float4 a = *(const float4*)(qp + s * 16 + h * 8);
      float4 b = *(const float4*)(qp + s * 16 + h * 8 + 4);
      qf[s].w[0] = pkh(a.x * LOG2E, a.y * LOG2E);
      qf[s].w[1] = pkh(a.z * LOG2E, a.w * LOG2E);
      qf[s].w[2] = pkh(b.x * LOG2E, b.y * LOG2E);
      qf[s].w[3] = pkh(b.z * LOG2E, b.w * LOG2E);
    }
  }
  f32x16 oc[2] = {
    {0,0,0,0,0,0,0,0,0,0,0,0,0,0,0,0},
    {0,0,0,0,0,0,0,0,0,0,0,0,0,0,0,0}
  };
  float mrow = -1e30f;
  float lrow = 0.f;
  const U32H one = {0x3C003C00u};
  PREF(0);
  WRITE(0);
  for (int t = 0; t < NT; ++t) {
    const bool more = (t + 1 < NT);
    if (more) PREF(t + 1);
    __syncthreads();
    const int cb = t & 1;
    const UH8* ksc = KsB[cb];
    const UH8* vtc = VtB[cb];
    f32x16 sc[2];
    #pragma unroll
    for (int kvt = 0; kvt < 2; ++kvt) {
      f32x16 acc = {0,0,0,0,0,0,0,0,0,0,0,0,0,0,0,0};
      #pragma unroll
      for (int s = 0; s < 4; ++s) {
        UH8 af;
        af.v = ksc[kvt * 256 + eidx[s]].v;
        acc = __builtin_amdgcn_mfma_f32_32x32x16_f16(af.v, qf[s].v, acc, 0, 0, 0);
      }
      sc[kvt] = acc;
    }
    float u[8];
    #pragma unroll
    for (int j = 0; j < 8; ++j)
      u[j] = fmaxf(fmaxf(sc[0][j], sc[0][j + 8]), fmaxf(sc[1][j], sc[1][j + 8]));
    #pragma unroll
    for (int j = 0; j < 4; ++j) u[j] = fmaxf(u[j], u[j + 4]);
    float pm = fmaxf(fmaxf(u[0], u[2]), fmaxf(u[1], u[3]));
    pm = fmaxf(pm, __shfl_xor(pm, 32, 64));
    if (__any(pm - mrow > THR_L2)) {
      const float mnew = fmaxf(mrow, pm);
      const float corr = __builtin_amdgcn_exp2f(mrow - mnew);
      #pragma unroll
      for (int dt = 0; dt < 2; ++dt)
        #pragma unroll
        for (int i = 0; i < 16; ++i)
          oc[dt][i] *= corr;
      lrow *= corr;
      mrow = mnew;
    }
    #pragma unroll
    for (int kvt = 0; kvt < 2; ++kvt)
      #pragma unroll
      for (int i = 0; i < 16; ++i)
        sc[kvt][i] = __builtin_amdgcn_exp2f(sc[kvt][i] - mrow);
    float ps = 0.f;
    #pragma unroll
    for (int s = 0; s < 4; ++s) {
      const int kvt = s >> 1;
      const int sr  = (s & 1) * 8;
      unsigned int LO0 = pkh(sc[kvt][sr + 0], sc[kvt][sr + 1]);
      unsigned int LO1 = pkh(sc[kvt][sr + 2], sc[kvt][sr + 3]);
      unsigned int HI0 = pkh(sc[kvt][sr + 4], sc[kvt][sr + 5]);
      unsigned int HI1 = pkh(sc[kvt][sr + 6], sc[kvt][sr + 7]);
      U32H c0 = {LO0}, c1 = {LO1}, c2 = {HI0}, c3 = {HI1};
      ps = __builtin_amdgcn_fdot2(c0.h, one.h, ps, false);
      ps = __builtin_amdgcn_fdot2(c1.h, one.h, ps, false);
      ps = __builtin_amdgcn_fdot2(c2.h, one.h, ps, false);
      ps = __builtin_amdgcn_fdot2(c3.h, one.h, ps, false);
      asm("v_permlane32_swap_b32 %0, %1" : "+v"(LO0), "+v"(HI0));
      asm("v_permlane32_swap_b32 %0, %1" : "+v"(LO1), "+v"(HI1));
      UH8 pf;
      pf.w[0] = LO0; pf.w[1] = LO1; pf.w[2] = HI0; pf.w[3] = HI1;
      #pragma unroll
      for (int dt = 0; dt < 2; ++dt) {
        UH8 vf;
        vf.v = vtc[dt * 256 + eidx[s]].v;
        oc[dt] = __builtin_amdgcn_mfma_f32_32x32x16_f16(vf.v, pf.v, oc[dt], 0, 0, 0);
      }
    }
    ps += __shfl_xor(ps, 32, 64);
    lrow += ps;
    if (more) WRITE(1 - cb);
  }
  const float inv = INV_D_QTR / lrow;
  float* orow = O + base + (size_t)(q0 + w * 32 + q32) * D_DIM;
  #pragma unroll
  for (int dt = 0; dt < 2; ++dt)
    #pragma unroll
    for (int r1 = 0; r1 < 4; ++r1) {
      f32x4 o = { oc[dt][4 * r1 + 0] * inv, oc[dt][4 * r1 + 1] * inv,
                  oc[dt][4 * r1 + 2] * inv, oc[dt][4 * r1 + 3] * inv };
      *(f32x4*)(orow + dt * 32 + 8 * r1 + 4 * h) = o;
    }
}

extern "C" void kernel_launch(void* const* d_in, const int* in_sizes, int n_in,
                              void* d_out, int out_size, void* d_ws, size_t ws_size,
                              hipStream_t stream) {
  const float* q = (const float*)d_in[0];
  const float* k = (const float*)d_in[1];
  const float* v = (const float*)d_in[2];
  float* o = (float*)d_out;
  const size_t need = 2ull * BH * 32 * NCHK * sizeof(UH8);   // 33.6 MB
  if (ws_size >= need) {
    prep_kv<<<dim3(BH * 32), dim3(256), 0, stream>>>(k, v, (UH8*)d_ws);
    attn_fwd2<<<dim3(1024), dim3(256), 0, stream>>>(q, (const UH8*)d_ws, o);
  } else {
    attn_fwd_fb<<<dim3(1024), dim3(256), 0, stream>>>(q, k, v, o);
  }
}